// Round 10
// baseline (181.309 us; speedup 1.0000x reference)
//
#include <hip/hip_runtime.h>
#include <hip/hip_bf16.h>

// Problem constants (reference: T=2048, B=2, D_MODEL=1024, H=16, HEAD_DIM=64)
#define TT 2048
#define BB 2
#define CC 1024
#define HH 16
#define DD 64
#define MM (TT * BB)   // 4096 rows in the projection GEMMs

typedef short bf16x8 __attribute__((ext_vector_type(8)));   // 8 bf16 in 4 VGPRs
typedef float f32x4  __attribute__((ext_vector_type(4)));

// float -> bf16 (round-nearest-even), bit-level
__device__ inline ushort f2b(float f) {
    union { float f; unsigned u; } v; v.f = f;
    unsigned r = v.u + 0x7FFFu + ((v.u >> 16) & 1u);
    return (ushort)(r >> 16);
}

// pack 2 floats -> 2 bf16 in one dword
__device__ inline unsigned pack_bf16(float a, float b) {
    __hip_bfloat162 h = __float22bfloat162_rn(make_float2(a, b));
    union { __hip_bfloat162 h; unsigned u; } c; c.h = h;
    return c.u;
}

// async global->LDS, 16B per lane
__device__ inline void gload_lds16(const ushort* g, ushort* l) {
    __builtin_amdgcn_global_load_lds(
        (const __attribute__((address_space(1))) void*)g,
        (__attribute__((address_space(3))) void*)l, 16, 0, 0);
}

// ---------------------------------------------------------------------------
// fp32 -> bf16 convert, x and all four W in one launch.
// ---------------------------------------------------------------------------
#define XQUADS (MM * CC / 4)          // 1048576
#define WQUADS (CC * CC / 4)          // 262144
__global__ __launch_bounds__(256) void conv_all(const float* __restrict__ x,
                                                const float* __restrict__ Wq,
                                                const float* __restrict__ Wk,
                                                const float* __restrict__ Wv,
                                                const float* __restrict__ Wo,
                                                ushort* __restrict__ dst) {
    int idx = blockIdx.x * 256 + threadIdx.x;    // quad index
    const float* src;
    int off;
    if (idx < XQUADS) {
        src = x; off = idx;
    } else {
        int wi = (idx - XQUADS) >> 18;           // WQUADS == 2^18
        off = (idx - XQUADS) & (WQUADS - 1);
        src = (wi == 0) ? Wq : (wi == 1) ? Wk : (wi == 2) ? Wv : Wo;
    }
    float4 v = ((const float4*)src)[off];
    ushort4 o = {f2b(v.x), f2b(v.y), f2b(v.z), f2b(v.w)};
    ((ushort4*)dst)[idx] = o;
}

// ---------------------------------------------------------------------------
// bf16 MFMA NT GEMM (m97 structure), 128x128 tile, BK=32, 4 waves (2x2).
// Fused QKV (grid.y = 24): wsel = by>>3 picks B/out.
// R10: prep_kv is FUSED into the epilogue — K and V are written directly in
// MFMA-fragment-major layout (the same scalar 2B stores as before, different
// addresses; closed-form inverse of prep_kv's maps, spot-checked):
//   K element (j = t&63, k = d):
//     off = (d>>5)*2048 + (j>>4)*512 + ((d>>3)&3)*128 + (j&15)*8 + (d&7)
//   V element (j = t&63, d), g = 4*(j>>4) + (j&3):
//     off = (g>>3)*2048 + (d>>4)*512 + ((j>>2)&3)*128 + (d&15)*8 + (g&7)
// within Kf/Vf[bh][tile=t>>6][4096]. Q scaled by 1/sqrt(64)*log2(e).
// Each 128-row block spans exactly one 64-key tile (t in [bm/2, bm/2+64)).
// ---------------------------------------------------------------------------
__global__ __launch_bounds__(256) void gemm_qkv(const ushort* __restrict__ A,
                                                const ushort* __restrict__ B0,
                                                const ushort* __restrict__ B1,
                                                const ushort* __restrict__ B2,
                                                ushort* __restrict__ Oq,
                                                ushort* __restrict__ Kf,
                                                ushort* __restrict__ Vf) {
    __shared__ __align__(16) ushort As[128 * 32];
    __shared__ __align__(16) ushort Bs[128 * 32];

    const int tid = threadIdx.x;
    const int wave = tid >> 6, lane = tid & 63;
    const int quad = lane >> 4, l16 = lane & 15;
    const int wm = wave >> 1, wn = wave & 1;

    const int bm = blockIdx.x * 128;
    const int by = blockIdx.y;
    const int wsel = by >> 3;
    const ushort* Bp = (wsel == 0) ? B0 : (wsel == 1) ? B1 : B2;
    const int bn = (by & 7) * 128;

    const int srow = lane >> 2;
    const int scol = (lane & 3) * 8;

    f32x4 acc[4][4];
#pragma unroll
    for (int i = 0; i < 4; i++)
#pragma unroll
        for (int j = 0; j < 4; j++) acc[i][j] = (f32x4){0.f, 0.f, 0.f, 0.f};

    for (int k0 = 0; k0 < CC; k0 += 32) {
#pragma unroll
        for (int i = 0; i < 2; i++) {
            const int rbase = wave * 32 + i * 16;
            gload_lds16(A + (size_t)(bm + rbase + srow) * CC + k0 + scol,
                        As + rbase * 32);
            gload_lds16(Bp + (size_t)(bn + rbase + srow) * CC + k0 + scol,
                        Bs + rbase * 32);
        }
        __syncthreads();

        bf16x8 af[4], bf[4];
#pragma unroll
        for (int mi = 0; mi < 4; mi++)
            af[mi] = *(const bf16x8*)(As + (wm * 64 + mi * 16 + l16) * 32 + quad * 8);
#pragma unroll
        for (int ni = 0; ni < 4; ni++)
            bf[ni] = *(const bf16x8*)(Bs + (wn * 64 + ni * 16 + l16) * 32 + quad * 8);
#pragma unroll
        for (int mi = 0; mi < 4; mi++)
#pragma unroll
            for (int ni = 0; ni < 4; ni++)
                acc[mi][ni] = __builtin_amdgcn_mfma_f32_16x16x32_bf16(
                    af[mi], bf[ni], acc[mi][ni], 0, 0, 0);
        __syncthreads();
    }

#pragma unroll
    for (int mi = 0; mi < 4; mi++) {
#pragma unroll
        for (int r = 0; r < 4; r++) {
            const int m = bm + wm * 64 + mi * 16 + quad * 4 + r;
            const int t = m >> 1, b = m & 1;
            const int j = t & 63;
            const size_t tbase = (size_t)(t >> 6) * 4096;
            if (wsel == 0) {
#pragma unroll
                for (int ni = 0; ni < 4; ni++) {
                    const int colg = bn + wn * 64 + ni * 16 + l16;
                    const int h = colg >> 6, d = colg & 63;
                    Oq[(((size_t)(b * HH + h)) * TT + t) * DD + d] =
                        f2b(acc[mi][ni][r] * 0.18033688f);  // 1/8 * log2(e)
                }
            } else if (wsel == 1) {
                const int nbp = (j >> 4) * 512 + (j & 15) * 8;   // j-invariant
#pragma unroll
                for (int ni = 0; ni < 4; ni++) {
                    const int cb = bn + wn * 64 + ni * 16;       // col base
                    const int h = cb >> 6;
                    const int dbase = cb & 63;                   // mult of 16
                    const size_t off = ((size_t)(b * HH + h)) * (TT * DD) + tbase
                        + (dbase >> 5) * 2048 + nbp
                        + (((dbase >> 3) & 3) + (l16 >> 3)) * 128 + (l16 & 7);
                    Kf[off] = f2b(acc[mi][ni][r]);
                }
            } else {
                const int g  = 4 * (j >> 4) + (j & 3);
                const int jp = ((j >> 2) & 3) * 128 + (g & 7);   // j-invariant
                const int cp = (g >> 3) * 2048;
#pragma unroll
                for (int ni = 0; ni < 4; ni++) {
                    const int cb = bn + wn * 64 + ni * 16;
                    const int h  = cb >> 6;
                    const int db = (cb >> 4) & 3;
                    const size_t off = ((size_t)(b * HH + h)) * (TT * DD) + tbase
                        + cp + db * 512 + jp + l16 * 8;
                    Vf[off] = f2b(acc[mi][ni][r]);
                }
            }
        }
    }
}

// ---------------------------------------------------------------------------
// Out-projection GEMM: 128x64 tile (512 blocks = 2/CU), BK=32, fp32 output.
// ---------------------------------------------------------------------------
__global__ __launch_bounds__(256) void gemm_out(const ushort* __restrict__ A,
                                                const ushort* __restrict__ Bm,
                                                float* __restrict__ Of) {
    __shared__ __align__(16) ushort As[128 * 32];   // 8 KB
    __shared__ __align__(16) ushort Bs[64 * 32];    // 4 KB

    const int tid = threadIdx.x;
    const int wave = tid >> 6, lane = tid & 63;
    const int quad = lane >> 4, l16 = lane & 15;

    const int bm = blockIdx.x * 128;
    const int bn = blockIdx.y * 64;

    const int srow = lane >> 2;
    const int scol = (lane & 3) * 8;

    f32x4 acc[2][4];
#pragma unroll
    for (int i = 0; i < 2; i++)
#pragma unroll
        for (int j = 0; j < 4; j++) acc[i][j] = (f32x4){0.f, 0.f, 0.f, 0.f};

    for (int k0 = 0; k0 < CC; k0 += 32) {
#pragma unroll
        for (int i = 0; i < 2; i++) {
            const int rbase = wave * 32 + i * 16;
            gload_lds16(A + (size_t)(bm + rbase + srow) * CC + k0 + scol,
                        As + rbase * 32);
        }
        gload_lds16(Bm + (size_t)(bn + wave * 16 + srow) * CC + k0 + scol,
                    Bs + wave * 16 * 32);
        __syncthreads();

        bf16x8 af[2], bf[4];
#pragma unroll
        for (int mi = 0; mi < 2; mi++)
            af[mi] = *(const bf16x8*)(As + (wave * 32 + mi * 16 + l16) * 32 + quad * 8);
#pragma unroll
        for (int ni = 0; ni < 4; ni++)
            bf[ni] = *(const bf16x8*)(Bs + (ni * 16 + l16) * 32 + quad * 8);
#pragma unroll
        for (int mi = 0; mi < 2; mi++)
#pragma unroll
            for (int ni = 0; ni < 4; ni++)
                acc[mi][ni] = __builtin_amdgcn_mfma_f32_16x16x32_bf16(
                    af[mi], bf[ni], acc[mi][ni], 0, 0, 0);
        __syncthreads();
    }

#pragma unroll
    for (int mi = 0; mi < 2; mi++)
#pragma unroll
        for (int r = 0; r < 4; r++) {
            const int m = bm + wave * 32 + mi * 16 + quad * 4 + r;
#pragma unroll
            for (int ni = 0; ni < 4; ni++)
                Of[(size_t)m * CC + bn + ni * 16 + l16] = acc[mi][ni][r];
        }
}

// ---------------------------------------------------------------------------
// Flash step with SWAPPED QK^T and fully in-register softmax.
//   S[nb] = mfma(kf[c*4+nb], qa[c], S[nb])  -> lane (quad,l16) holds
//   P[key=j0+16nb+4quad+r][query=q0+l16]: 16 P-values per lane, one query.
//   exp2 + l-sum in-lane; PV A-operand packed from the lane's own values
//   (V permutation kappa matches), 8 cvt_pk, zero cross-lane.
// ---------------------------------------------------------------------------
template <bool DIAG>
__device__ __forceinline__ void attn_step(const bf16x8* qa, f32x4* O, float& l,
                                          const bf16x8* kf, const bf16x8* vf,
                                          int j0, int qg, int quad) {
    f32x4 S[4];
#pragma unroll
    for (int nb = 0; nb < 4; nb++) S[nb] = (f32x4){0.f, 0.f, 0.f, 0.f};
#pragma unroll
    for (int c = 0; c < 2; c++)
#pragma unroll
        for (int nb = 0; nb < 4; nb++)
            S[nb] = __builtin_amdgcn_mfma_f32_16x16x32_bf16(kf[c * 4 + nb],
                                                            qa[c], S[nb], 0, 0, 0);

    float p[4][4];   // [nb][r], key = j0 + nb*16 + quad*4 + r
#pragma unroll
    for (int nb = 0; nb < 4; nb++)
#pragma unroll
        for (int r = 0; r < 4; r++) {
            float s = S[nb][r];
            if (DIAG) { if (j0 + nb * 16 + quad * 4 + r > qg) s = -1e30f; }
            p[nb][r] = __builtin_amdgcn_exp2f(s);
        }
#pragma unroll
    for (int nb = 0; nb < 4; nb++)
        l += (p[nb][0] + p[nb][1]) + (p[nb][2] + p[nb][3]);

    // PV A-operand: dword w of pa[c] covers kslots u=2w,2w+1 ->
    // nb = 2c + (w>>1), r = (w&1)*2 + {0,1}  (matches kappa layout)
    union { unsigned w[4]; bf16x8 v; } pa0, pa1;
#pragma unroll
    for (int w = 0; w < 4; w++) {
        const int nb = w >> 1;
        const int rb = (w & 1) * 2;
        pa0.w[w] = pack_bf16(p[nb][rb], p[nb][rb + 1]);
        pa1.w[w] = pack_bf16(p[2 + nb][rb], p[2 + nb][rb + 1]);
    }
#pragma unroll
    for (int db = 0; db < 4; db++)
        O[db] = __builtin_amdgcn_mfma_f32_16x16x32_bf16(pa0.v, vf[db], O[db], 0, 0, 0);
#pragma unroll
    for (int db = 0; db < 4; db++)
        O[db] = __builtin_amdgcn_mfma_f32_16x16x32_bf16(pa1.v, vf[4 + db], O[db], 0, 0, 0);
}

// ---------------------------------------------------------------------------
// Paired-tile flash MFMA attention: in-register softmax + LDS-staged K/V
// double-buffer (the R7 known-best structure, reverted verbatim after R8/R9
// regressions: M_w=64@1blk/CU exposed chain latency; key-split added idle
// diagonal waves + epilogue combine for no gain).
// LDS: 2 x 16KB = 32KB/block, 2 blocks/CU. XCD decode: xcd owns bh in
// [4*xcd, 4*xcd+4) (2MB K/V per L2).
// ---------------------------------------------------------------------------
__global__ __launch_bounds__(256, 2) void attn_mfma(const ushort* __restrict__ Qb,
                                                    const ushort* __restrict__ Kf,
                                                    const ushort* __restrict__ Vf,
                                                    ushort* __restrict__ ctx) {
    __shared__ __align__(16) ushort KV[2][8192];  // [buf][chunks 0-7 K, 8-15 V]

    const int tid  = threadIdx.x;
    const int wave = tid >> 6;
    const int lane = tid & 63;
    const int quad = lane >> 4;
    const int l16  = lane & 15;

    // XCD-locality decode: xcd = bidx&7 owns bh in [4*xcd, 4*xcd+4)
    const int bidx = blockIdx.x;                  // 0..511
    const int xcd  = bidx & 7;
    const int slot = bidx >> 3;                   // 0..63
    const int bh   = xcd * 4 + (slot >> 4);       // 0..31
    const int p    = slot & 15;                   // 0..15

    const int qtA = p, qtB = (TT / 64 - 1) - p;   // qtA < 16 <= qtB
    const int q0A = qtA * 64 + wave * 16;
    const int q0B = qtB * 64 + wave * 16;
    const int qgA = q0A + l16;                    // this lane's A query
    const int qgB = q0B + l16;                    // this lane's B query

    const size_t baseQK = (size_t)bh * TT * DD;

    bf16x8 qaA[2], qaB[2];
    {
        const ushort* qp = Qb + baseQK + (size_t)(q0A + l16) * DD + quad * 8;
        qaA[0] = *(const bf16x8*)(qp);
        qaA[1] = *(const bf16x8*)(qp + 32);
        const ushort* qp2 = Qb + baseQK + (size_t)(q0B + l16) * DD + quad * 8;
        qaB[0] = *(const bf16x8*)(qp2);
        qaB[1] = *(const bf16x8*)(qp2 + 32);
    }

    f32x4 OA[4], OB[4];
#pragma unroll
    for (int i = 0; i < 4; i++) {
        OA[i] = (f32x4){0.f, 0.f, 0.f, 0.f};
        OB[i] = (f32x4){0.f, 0.f, 0.f, 0.f};
    }
    float lA = 0.f, lB = 0.f;   // per-lane partial denom (query = q0+l16)

    const ushort* Kfp = Kf + baseQK;   // +4096 per tile
    const ushort* Vfp = Vf + baseQK;

    // stage one 16KB K/V tile into KV[buf]: wave w DMAs K chunks {2w,2w+1}
    // and V chunks {2w,2w+1} (wave-uniform LDS base + lane*16B, linear).
    auto stage = [&](int buf, const ushort* kp, const ushort* vp) {
#pragma unroll
        for (int i = 0; i < 2; i++) {
            const int ch = wave * 2 + i;           // 0..7 across 4 waves
            gload_lds16(kp + (ch << 9) + lane * 8, &KV[buf][ch << 9]);
            gload_lds16(vp + (ch << 9) + lane * 8, &KV[buf][(8 + ch) << 9]);
        }
    };

    stage(0, Kfp, Vfp);
    __syncthreads();

    int cur = 0;
    for (int kt = 0; kt <= qtB; kt++) {
        // issue next tile's DMA before touching this tile's data
        if (kt < qtB) stage(cur ^ 1, Kfp + 4096, Vfp + 4096);

        // fragment loads from LDS: contiguous 1KB per chunk, lane*16B apart
        bf16x8 kf[8], vf[8];
#pragma unroll
        for (int i = 0; i < 8; i++) {
            kf[i] = *(const bf16x8*)(&KV[cur][i << 9] + lane * 8);
            vf[i] = *(const bf16x8*)(&KV[cur][(8 + i) << 9] + lane * 8);
        }

        const int j0 = kt * 64;
        if (kt == qtB)
            attn_step<true >(qaB, OB, lB, kf, vf, j0, qgB, quad);
        else
            attn_step<false>(qaB, OB, lB, kf, vf, j0, qgB, quad);

        if (kt < qtA)
            attn_step<false>(qaA, OA, lA, kf, vf, j0, qgA, quad);
        else if (kt == qtA)
            attn_step<true >(qaA, OA, lA, kf, vf, j0, qgA, quad);

        __syncthreads();   // publishes buf cur^1; protects cur for overwrite
        cur ^= 1;
        Kfp += 4096;
        Vfp += 4096;
    }

    // epilogue: complete l across the 4 quads holding this query's keys,
    // then fetch the denom for the queries THIS lane's O rows belong to.
    lA += __shfl_xor(lA, 16); lA += __shfl_xor(lA, 32);
    lB += __shfl_xor(lB, 16); lB += __shfl_xor(lB, 32);

    const int b = bh >> 4, h = bh & 15;
#pragma unroll
    for (int r = 0; r < 4; r++) {
        const float invA = 1.f / __shfl(lA, quad * 4 + r);
        const float invB = 1.f / __shfl(lB, quad * 4 + r);
        const int tA = q0A + quad * 4 + r;
        const int tB = q0B + quad * 4 + r;
#pragma unroll
        for (int db = 0; db < 4; db++) {
            ctx[((size_t)tA * BB + b) * CC + h * DD + db * 16 + l16] =
                f2b(OA[db][r] * invA);
            ctx[((size_t)tB * BB + b) * CC + h * DD + db * 16 + l16] =
                f2b(OB[db][r] * invB);
        }
    }
}

// ---------------------------------------------------------------------------
extern "C" void kernel_launch(void* const* d_in, const int* in_sizes, int n_in,
                              void* d_out, int out_size, void* d_ws, size_t ws_size,
                              hipStream_t stream) {
    const float* x  = (const float*)d_in[0];
    const float* Wq = (const float*)d_in[1];
    const float* Wk = (const float*)d_in[2];
    const float* Wv = (const float*)d_in[3];
    const float* Wo = (const float*)d_in[4];
    float* out = (float*)d_out;

    // Workspace (bf16): xb 8MB | Wb 8MB | Qb 8 | Kf 8 | Vf 8 | Ctxb 8 = 48MB
    ushort* xb  = (ushort*)d_ws;
    ushort* Wb  = xb + (size_t)MM * CC;
    ushort* Wqb = Wb;
    ushort* Wkb = Wb + (size_t)CC * CC;
    ushort* Wvb = Wb + 2 * (size_t)CC * CC;
    ushort* Wob = Wb + 3 * (size_t)CC * CC;
    ushort* Qb  = Wb + 4 * (size_t)CC * CC;
    ushort* Kf  = Qb + (size_t)MM * CC;
    ushort* Vf  = Kf + (size_t)MM * CC;
    ushort* Ctxb = Vf + (size_t)MM * CC;

    conv_all<<<dim3((XQUADS + 4 * WQUADS) / 256), 256, 0, stream>>>(
        x, Wq, Wk, Wv, Wo, xb);

    gemm_qkv<<<dim3(MM / 128, 24), 256, 0, stream>>>(
        xb, Wqb, Wkb, Wvb, Qb, Kf, Vf);

    attn_mfma<<<dim3(512), 256, 0, stream>>>(Qb, Kf, Vf, Ctxb);

    gemm_out<<<dim3(MM / 128, CC / 64), 256, 0, stream>>>(Ctxb, Wob, out);
}

// Round 11
// 178.668 us; speedup vs baseline: 1.0148x; 1.0148x over previous
//
#include <hip/hip_runtime.h>
#include <hip/hip_bf16.h>

// Problem constants (reference: T=2048, B=2, D_MODEL=1024, H=16, HEAD_DIM=64)
#define TT 2048
#define BB 2
#define CC 1024
#define HH 16
#define DD 64
#define MM (TT * BB)   // 4096 rows in the projection GEMMs

typedef short bf16x8 __attribute__((ext_vector_type(8)));   // 8 bf16 in 4 VGPRs
typedef float f32x4  __attribute__((ext_vector_type(4)));

// float -> bf16 (round-nearest-even), bit-level
__device__ inline ushort f2b(float f) {
    union { float f; unsigned u; } v; v.f = f;
    unsigned r = v.u + 0x7FFFu + ((v.u >> 16) & 1u);
    return (ushort)(r >> 16);
}

// pack 2 floats -> 2 bf16 in one dword
__device__ inline unsigned pack_bf16(float a, float b) {
    __hip_bfloat162 h = __float22bfloat162_rn(make_float2(a, b));
    union { __hip_bfloat162 h; unsigned u; } c; c.h = h;
    return c.u;
}

// async global->LDS, 16B per lane
__device__ inline void gload_lds16(const ushort* g, ushort* l) {
    __builtin_amdgcn_global_load_lds(
        (const __attribute__((address_space(1))) void*)g,
        (__attribute__((address_space(3))) void*)l, 16, 0, 0);
}

// ---------------------------------------------------------------------------
// fp32 -> bf16 convert, x and all four W in one launch.
// ---------------------------------------------------------------------------
#define XQUADS (MM * CC / 4)          // 1048576
#define WQUADS (CC * CC / 4)          // 262144
__global__ __launch_bounds__(256) void conv_all(const float* __restrict__ x,
                                                const float* __restrict__ Wq,
                                                const float* __restrict__ Wk,
                                                const float* __restrict__ Wv,
                                                const float* __restrict__ Wo,
                                                ushort* __restrict__ dst) {
    int idx = blockIdx.x * 256 + threadIdx.x;    // quad index
    const float* src;
    int off;
    if (idx < XQUADS) {
        src = x; off = idx;
    } else {
        int wi = (idx - XQUADS) >> 18;           // WQUADS == 2^18
        off = (idx - XQUADS) & (WQUADS - 1);
        src = (wi == 0) ? Wq : (wi == 1) ? Wk : (wi == 2) ? Wv : Wo;
    }
    float4 v = ((const float4*)src)[off];
    ushort4 o = {f2b(v.x), f2b(v.y), f2b(v.z), f2b(v.w)};
    ((ushort4*)dst)[idx] = o;
}

// ---------------------------------------------------------------------------
// bf16 MFMA NT GEMM (m97 structure), 128x128 tile, BK=32, 4 waves (2x2).
// Fused QKV (grid.y = 24): wsel = by>>3 picks B/out.
// R11: prep_kv stays fused, but K/V epilogue now round-trips through LDS
// (As/Bs are dead after the K-loop's final barrier): scatter acc into the
// fragment-major layout in LDS per b-phase, then stream 1024 x 16B fully
// coalesced chunks to global. R10's direct scalar stores were 2B at 16B
// stride (16 sectors per 16 lanes) — that was the +17us regression.
// Maps (harness-verified in R10):
//   K (j = t&63, k = d): off = (d>>5)*2048 + (j>>4)*512 + ((d>>3)&3)*128
//                              + (j&15)*8 + (d&7)
//   V (j, d), g = 4*(j>>4)+(j&3): off = (g>>3)*2048 + (d>>4)*512
//                              + ((j>>2)&3)*128 + (d&15)*8 + (g&7)
// b = r&1 (m = bm + wm*64 + mi*16 + quad*4 + r). Q scaled by 0.125*log2e.
// ---------------------------------------------------------------------------
__global__ __launch_bounds__(256) void gemm_qkv(const ushort* __restrict__ A,
                                                const ushort* __restrict__ B0,
                                                const ushort* __restrict__ B1,
                                                const ushort* __restrict__ B2,
                                                ushort* __restrict__ Oq,
                                                ushort* __restrict__ Kf,
                                                ushort* __restrict__ Vf) {
    __shared__ __align__(16) ushort As[128 * 32];
    __shared__ __align__(16) ushort Bs[128 * 32];

    const int tid = threadIdx.x;
    const int wave = tid >> 6, lane = tid & 63;
    const int quad = lane >> 4, l16 = lane & 15;
    const int wm = wave >> 1, wn = wave & 1;

    const int bm = blockIdx.x * 128;
    const int by = blockIdx.y;
    const int wsel = by >> 3;
    const ushort* Bp = (wsel == 0) ? B0 : (wsel == 1) ? B1 : B2;
    const int bn = (by & 7) * 128;

    const int srow = lane >> 2;
    const int scol = (lane & 3) * 8;

    f32x4 acc[4][4];
#pragma unroll
    for (int i = 0; i < 4; i++)
#pragma unroll
        for (int j = 0; j < 4; j++) acc[i][j] = (f32x4){0.f, 0.f, 0.f, 0.f};

    for (int k0 = 0; k0 < CC; k0 += 32) {
#pragma unroll
        for (int i = 0; i < 2; i++) {
            const int rbase = wave * 32 + i * 16;
            gload_lds16(A + (size_t)(bm + rbase + srow) * CC + k0 + scol,
                        As + rbase * 32);
            gload_lds16(Bp + (size_t)(bn + rbase + srow) * CC + k0 + scol,
                        Bs + rbase * 32);
        }
        __syncthreads();

        bf16x8 af[4], bf[4];
#pragma unroll
        for (int mi = 0; mi < 4; mi++)
            af[mi] = *(const bf16x8*)(As + (wm * 64 + mi * 16 + l16) * 32 + quad * 8);
#pragma unroll
        for (int ni = 0; ni < 4; ni++)
            bf[ni] = *(const bf16x8*)(Bs + (wn * 64 + ni * 16 + l16) * 32 + quad * 8);
#pragma unroll
        for (int mi = 0; mi < 4; mi++)
#pragma unroll
            for (int ni = 0; ni < 4; ni++)
                acc[mi][ni] = __builtin_amdgcn_mfma_f32_16x16x32_bf16(
                    af[mi], bf[ni], acc[mi][ni], 0, 0, 0);
        __syncthreads();
    }

    if (wsel == 0) {
        // Q: direct scatter (16 lanes write 32 contiguous bytes — OK)
#pragma unroll
        for (int mi = 0; mi < 4; mi++)
#pragma unroll
            for (int r = 0; r < 4; r++) {
                const int m = bm + wm * 64 + mi * 16 + quad * 4 + r;
                const int t = m >> 1, b = m & 1;
#pragma unroll
                for (int ni = 0; ni < 4; ni++) {
                    const int colg = bn + wn * 64 + ni * 16 + l16;
                    const int h = colg >> 6, d = colg & 63;
                    Oq[(((size_t)(b * HH + h)) * TT + t) * DD + d] =
                        f2b(acc[mi][ni][r] * 0.18033688f);  // 1/8 * log2(e)
                }
            }
    } else {
        // K/V: LDS-transpose epilogue. Phase = b (= r&1). Per phase, the
        // 64x128 (j x [2 heads][64 d]) slab lives in As (wn=0 head) + Bs
        // (wn=1 head), then streams out as 1024 coalesced 16B chunks.
        ushort* L = wn ? Bs : As;
        ushort* dstp = (wsel == 1) ? Kf : Vf;
        const int tile = blockIdx.x;          // (m>>1)>>6
        const int h0 = bn >> 6;
#pragma unroll
        for (int phase = 0; phase < 2; phase++) {
#pragma unroll
            for (int mi = 0; mi < 4; mi++)
#pragma unroll
                for (int rr = 0; rr < 2; rr++) {
                    const int r = rr * 2 + phase;
                    const int j = wm * 32 + mi * 8 + quad * 2 + rr;
                    int offj;
                    if (wsel == 1) {
                        offj = (j >> 4) * 512 + (j & 15) * 8;
                    } else {
                        const int g = 4 * (j >> 4) + (j & 3);
                        offj = (g >> 3) * 2048 + ((j >> 2) & 3) * 128 + (g & 7);
                    }
#pragma unroll
                    for (int ni = 0; ni < 4; ni++) {
                        const int d = ni * 16 + l16;
                        int off;
                        if (wsel == 1)
                            off = (d >> 5) * 2048 + offj +
                                  (((d >> 3) & 3)) * 128 + (d & 7);
                        else
                            off = offj + (d >> 4) * 512 + (d & 15) * 8;
                        L[off] = f2b(acc[mi][ni][r]);
                    }
                }
            __syncthreads();
            // coalesced writeout: 1024 chunks x 16B (8192 ushorts)
#pragma unroll
            for (int i = 0; i < 4; i++) {
                const int o = tid + i * 256;              // 0..1023
                const int wno = o >> 9;                   // head half
                const int idx = o & 511;                  // 16B chunk in half
                const ushort* src = (wno ? Bs : As) + idx * 8;
                const size_t goff =
                    ((size_t)(phase * HH + h0 + wno)) * (TT * DD) +
                    (size_t)tile * 4096 + (size_t)idx * 8;
                *(uint4*)(dstp + goff) = *(const uint4*)src;
            }
            __syncthreads();
        }
    }
}

// ---------------------------------------------------------------------------
// Out-projection GEMM: 128x64 tile (512 blocks = 2/CU), BK=32, fp32 output.
// ---------------------------------------------------------------------------
__global__ __launch_bounds__(256) void gemm_out(const ushort* __restrict__ A,
                                                const ushort* __restrict__ Bm,
                                                float* __restrict__ Of) {
    __shared__ __align__(16) ushort As[128 * 32];   // 8 KB
    __shared__ __align__(16) ushort Bs[64 * 32];    // 4 KB

    const int tid = threadIdx.x;
    const int wave = tid >> 6, lane = tid & 63;
    const int quad = lane >> 4, l16 = lane & 15;

    const int bm = blockIdx.x * 128;
    const int bn = blockIdx.y * 64;

    const int srow = lane >> 2;
    const int scol = (lane & 3) * 8;

    f32x4 acc[2][4];
#pragma unroll
    for (int i = 0; i < 2; i++)
#pragma unroll
        for (int j = 0; j < 4; j++) acc[i][j] = (f32x4){0.f, 0.f, 0.f, 0.f};

    for (int k0 = 0; k0 < CC; k0 += 32) {
#pragma unroll
        for (int i = 0; i < 2; i++) {
            const int rbase = wave * 32 + i * 16;
            gload_lds16(A + (size_t)(bm + rbase + srow) * CC + k0 + scol,
                        As + rbase * 32);
        }
        gload_lds16(Bm + (size_t)(bn + wave * 16 + srow) * CC + k0 + scol,
                    Bs + wave * 16 * 32);
        __syncthreads();

        bf16x8 af[2], bf[4];
#pragma unroll
        for (int mi = 0; mi < 2; mi++)
            af[mi] = *(const bf16x8*)(As + (wave * 32 + mi * 16 + l16) * 32 + quad * 8);
#pragma unroll
        for (int ni = 0; ni < 4; ni++)
            bf[ni] = *(const bf16x8*)(Bs + (ni * 16 + l16) * 32 + quad * 8);
#pragma unroll
        for (int mi = 0; mi < 2; mi++)
#pragma unroll
            for (int ni = 0; ni < 4; ni++)
                acc[mi][ni] = __builtin_amdgcn_mfma_f32_16x16x32_bf16(
                    af[mi], bf[ni], acc[mi][ni], 0, 0, 0);
        __syncthreads();
    }

#pragma unroll
    for (int mi = 0; mi < 2; mi++)
#pragma unroll
        for (int r = 0; r < 4; r++) {
            const int m = bm + wave * 32 + mi * 16 + quad * 4 + r;
#pragma unroll
            for (int ni = 0; ni < 4; ni++)
                Of[(size_t)m * CC + bn + ni * 16 + l16] = acc[mi][ni][r];
        }
}

// ---------------------------------------------------------------------------
// Flash step with SWAPPED QK^T and fully in-register softmax.
//   S[nb] = mfma(kf[c*4+nb], qa[c], S[nb])  -> lane (quad,l16) holds
//   P[key=j0+16nb+4quad+r][query=q0+l16]: 16 P-values per lane, one query.
//   exp2 + l-sum in-lane; PV A-operand packed from the lane's own values
//   (V permutation kappa matches), 8 cvt_pk, zero cross-lane.
// ---------------------------------------------------------------------------
template <bool DIAG>
__device__ __forceinline__ void attn_step(const bf16x8* qa, f32x4* O, float& l,
                                          const bf16x8* kf, const bf16x8* vf,
                                          int j0, int qg, int quad) {
    f32x4 S[4];
#pragma unroll
    for (int nb = 0; nb < 4; nb++) S[nb] = (f32x4){0.f, 0.f, 0.f, 0.f};
#pragma unroll
    for (int c = 0; c < 2; c++)
#pragma unroll
        for (int nb = 0; nb < 4; nb++)
            S[nb] = __builtin_amdgcn_mfma_f32_16x16x32_bf16(kf[c * 4 + nb],
                                                            qa[c], S[nb], 0, 0, 0);

    float p[4][4];   // [nb][r], key = j0 + nb*16 + quad*4 + r
#pragma unroll
    for (int nb = 0; nb < 4; nb++)
#pragma unroll
        for (int r = 0; r < 4; r++) {
            float s = S[nb][r];
            if (DIAG) { if (j0 + nb * 16 + quad * 4 + r > qg) s = -1e30f; }
            p[nb][r] = __builtin_amdgcn_exp2f(s);
        }
#pragma unroll
    for (int nb = 0; nb < 4; nb++)
        l += (p[nb][0] + p[nb][1]) + (p[nb][2] + p[nb][3]);

    // PV A-operand: dword w of pa[c] covers kslots u=2w,2w+1 ->
    // nb = 2c + (w>>1), r = (w&1)*2 + {0,1}  (matches kappa layout)
    union { unsigned w[4]; bf16x8 v; } pa0, pa1;
#pragma unroll
    for (int w = 0; w < 4; w++) {
        const int nb = w >> 1;
        const int rb = (w & 1) * 2;
        pa0.w[w] = pack_bf16(p[nb][rb], p[nb][rb + 1]);
        pa1.w[w] = pack_bf16(p[2 + nb][rb], p[2 + nb][rb + 1]);
    }
#pragma unroll
    for (int db = 0; db < 4; db++)
        O[db] = __builtin_amdgcn_mfma_f32_16x16x32_bf16(pa0.v, vf[db], O[db], 0, 0, 0);
#pragma unroll
    for (int db = 0; db < 4; db++)
        O[db] = __builtin_amdgcn_mfma_f32_16x16x32_bf16(pa1.v, vf[4 + db], O[db], 0, 0, 0);
}

// ---------------------------------------------------------------------------
// Paired-tile flash MFMA attention: in-register softmax + LDS-staged K/V
// double-buffer (R7 known-best structure, unchanged).
// LDS: 2 x 16KB = 32KB/block, 2 blocks/CU. XCD decode: xcd owns bh in
// [4*xcd, 4*xcd+4) (2MB K/V per L2).
// ---------------------------------------------------------------------------
__global__ __launch_bounds__(256, 2) void attn_mfma(const ushort* __restrict__ Qb,
                                                    const ushort* __restrict__ Kf,
                                                    const ushort* __restrict__ Vf,
                                                    ushort* __restrict__ ctx) {
    __shared__ __align__(16) ushort KV[2][8192];  // [buf][chunks 0-7 K, 8-15 V]

    const int tid  = threadIdx.x;
    const int wave = tid >> 6;
    const int lane = tid & 63;
    const int quad = lane >> 4;
    const int l16  = lane & 15;

    // XCD-locality decode: xcd = bidx&7 owns bh in [4*xcd, 4*xcd+4)
    const int bidx = blockIdx.x;                  // 0..511
    const int xcd  = bidx & 7;
    const int slot = bidx >> 3;                   // 0..63
    const int bh   = xcd * 4 + (slot >> 4);       // 0..31
    const int p    = slot & 15;                   // 0..15

    const int qtA = p, qtB = (TT / 64 - 1) - p;   // qtA < 16 <= qtB
    const int q0A = qtA * 64 + wave * 16;
    const int q0B = qtB * 64 + wave * 16;
    const int qgA = q0A + l16;                    // this lane's A query
    const int qgB = q0B + l16;                    // this lane's B query

    const size_t baseQK = (size_t)bh * TT * DD;

    bf16x8 qaA[2], qaB[2];
    {
        const ushort* qp = Qb + baseQK + (size_t)(q0A + l16) * DD + quad * 8;
        qaA[0] = *(const bf16x8*)(qp);
        qaA[1] = *(const bf16x8*)(qp + 32);
        const ushort* qp2 = Qb + baseQK + (size_t)(q0B + l16) * DD + quad * 8;
        qaB[0] = *(const bf16x8*)(qp2);
        qaB[1] = *(const bf16x8*)(qp2 + 32);
    }

    f32x4 OA[4], OB[4];
#pragma unroll
    for (int i = 0; i < 4; i++) {
        OA[i] = (f32x4){0.f, 0.f, 0.f, 0.f};
        OB[i] = (f32x4){0.f, 0.f, 0.f, 0.f};
    }
    float lA = 0.f, lB = 0.f;   // per-lane partial denom (query = q0+l16)

    const ushort* Kfp = Kf + baseQK;   // +4096 per tile
    const ushort* Vfp = Vf + baseQK;

    // stage one 16KB K/V tile into KV[buf]: wave w DMAs K chunks {2w,2w+1}
    // and V chunks {2w,2w+1} (wave-uniform LDS base + lane*16B, linear).
    auto stage = [&](int buf, const ushort* kp, const ushort* vp) {
#pragma unroll
        for (int i = 0; i < 2; i++) {
            const int ch = wave * 2 + i;           // 0..7 across 4 waves
            gload_lds16(kp + (ch << 9) + lane * 8, &KV[buf][ch << 9]);
            gload_lds16(vp + (ch << 9) + lane * 8, &KV[buf][(8 + ch) << 9]);
        }
    };

    stage(0, Kfp, Vfp);
    __syncthreads();

    int cur = 0;
    for (int kt = 0; kt <= qtB; kt++) {
        // issue next tile's DMA before touching this tile's data
        if (kt < qtB) stage(cur ^ 1, Kfp + 4096, Vfp + 4096);

        // fragment loads from LDS: contiguous 1KB per chunk, lane*16B apart
        bf16x8 kf[8], vf[8];
#pragma unroll
        for (int i = 0; i < 8; i++) {
            kf[i] = *(const bf16x8*)(&KV[cur][i << 9] + lane * 8);
            vf[i] = *(const bf16x8*)(&KV[cur][(8 + i) << 9] + lane * 8);
        }

        const int j0 = kt * 64;
        if (kt == qtB)
            attn_step<true >(qaB, OB, lB, kf, vf, j0, qgB, quad);
        else
            attn_step<false>(qaB, OB, lB, kf, vf, j0, qgB, quad);

        if (kt < qtA)
            attn_step<false>(qaA, OA, lA, kf, vf, j0, qgA, quad);
        else if (kt == qtA)
            attn_step<true >(qaA, OA, lA, kf, vf, j0, qgA, quad);

        __syncthreads();   // publishes buf cur^1; protects cur for overwrite
        cur ^= 1;
        Kfp += 4096;
        Vfp += 4096;
    }

    // epilogue: complete l across the 4 quads holding this query's keys,
    // then fetch the denom for the queries THIS lane's O rows belong to.
    lA += __shfl_xor(lA, 16); lA += __shfl_xor(lA, 32);
    lB += __shfl_xor(lB, 16); lB += __shfl_xor(lB, 32);

    const int b = bh >> 4, h = bh & 15;
#pragma unroll
    for (int r = 0; r < 4; r++) {
        const float invA = 1.f / __shfl(lA, quad * 4 + r);
        const float invB = 1.f / __shfl(lB, quad * 4 + r);
        const int tA = q0A + quad * 4 + r;
        const int tB = q0B + quad * 4 + r;
#pragma unroll
        for (int db = 0; db < 4; db++) {
            ctx[((size_t)tA * BB + b) * CC + h * DD + db * 16 + l16] =
                f2b(OA[db][r] * invA);
            ctx[((size_t)tB * BB + b) * CC + h * DD + db * 16 + l16] =
                f2b(OB[db][r] * invB);
        }
    }
}

// ---------------------------------------------------------------------------
extern "C" void kernel_launch(void* const* d_in, const int* in_sizes, int n_in,
                              void* d_out, int out_size, void* d_ws, size_t ws_size,
                              hipStream_t stream) {
    const float* x  = (const float*)d_in[0];
    const float* Wq = (const float*)d_in[1];
    const float* Wk = (const float*)d_in[2];
    const float* Wv = (const float*)d_in[3];
    const float* Wo = (const float*)d_in[4];
    float* out = (float*)d_out;

    // Workspace (bf16): xb 8MB | Wb 8MB | Qb 8 | Kf 8 | Vf 8 | Ctxb 8 = 48MB
    ushort* xb  = (ushort*)d_ws;
    ushort* Wb  = xb + (size_t)MM * CC;
    ushort* Wqb = Wb;
    ushort* Wkb = Wb + (size_t)CC * CC;
    ushort* Wvb = Wb + 2 * (size_t)CC * CC;
    ushort* Wob = Wb + 3 * (size_t)CC * CC;
    ushort* Qb  = Wb + 4 * (size_t)CC * CC;
    ushort* Kf  = Qb + (size_t)MM * CC;
    ushort* Vf  = Kf + (size_t)MM * CC;
    ushort* Ctxb = Vf + (size_t)MM * CC;

    conv_all<<<dim3((XQUADS + 4 * WQUADS) / 256), 256, 0, stream>>>(
        x, Wq, Wk, Wv, Wo, xb);

    gemm_qkv<<<dim3(MM / 128, 24), 256, 0, stream>>>(
        xb, Wqb, Wkb, Wvb, Qb, Kf, Vf);

    attn_mfma<<<dim3(512), 256, 0, stream>>>(Qb, Kf, Vf, Ctxb);

    gemm_out<<<dim3(MM / 128, CC / 64), 256, 0, stream>>>(Ctxb, Wob, out);
}

// Round 12
// 171.095 us; speedup vs baseline: 1.0597x; 1.0443x over previous
//
#include <hip/hip_runtime.h>
#include <hip/hip_bf16.h>

// Problem constants (reference: T=2048, B=2, D_MODEL=1024, H=16, HEAD_DIM=64)
#define TT 2048
#define BB 2
#define CC 1024
#define HH 16
#define DD 64
#define MM (TT * BB)   // 4096 rows in the projection GEMMs

typedef short bf16x8 __attribute__((ext_vector_type(8)));   // 8 bf16 in 4 VGPRs
typedef float f32x4  __attribute__((ext_vector_type(4)));

// float -> bf16 (round-nearest-even), bit-level
__device__ inline ushort f2b(float f) {
    union { float f; unsigned u; } v; v.f = f;
    unsigned r = v.u + 0x7FFFu + ((v.u >> 16) & 1u);
    return (ushort)(r >> 16);
}

// pack 2 floats -> 2 bf16 in one dword
__device__ inline unsigned pack_bf16(float a, float b) {
    __hip_bfloat162 h = __float22bfloat162_rn(make_float2(a, b));
    union { __hip_bfloat162 h; unsigned u; } c; c.h = h;
    return c.u;
}

// async global->LDS, 16B per lane
__device__ inline void gload_lds16(const ushort* g, ushort* l) {
    __builtin_amdgcn_global_load_lds(
        (const __attribute__((address_space(1))) void*)g,
        (__attribute__((address_space(3))) void*)l, 16, 0, 0);
}

// ---------------------------------------------------------------------------
// fp32 -> bf16 convert, x and all four W in one launch.
// ---------------------------------------------------------------------------
#define XQUADS (MM * CC / 4)          // 1048576
#define WQUADS (CC * CC / 4)          // 262144
__global__ __launch_bounds__(256) void conv_all(const float* __restrict__ x,
                                                const float* __restrict__ Wq,
                                                const float* __restrict__ Wk,
                                                const float* __restrict__ Wv,
                                                const float* __restrict__ Wo,
                                                ushort* __restrict__ dst) {
    int idx = blockIdx.x * 256 + threadIdx.x;    // quad index
    const float* src;
    int off;
    if (idx < XQUADS) {
        src = x; off = idx;
    } else {
        int wi = (idx - XQUADS) >> 18;           // WQUADS == 2^18
        off = (idx - XQUADS) & (WQUADS - 1);
        src = (wi == 0) ? Wq : (wi == 1) ? Wk : (wi == 2) ? Wv : Wo;
    }
    float4 v = ((const float4*)src)[off];
    ushort4 o = {f2b(v.x), f2b(v.y), f2b(v.z), f2b(v.w)};
    ((ushort4*)dst)[idx] = o;
}

// ---------------------------------------------------------------------------
// bf16 MFMA NT GEMM (m97 structure), 128x128 tile, BK=32, 4 waves (2x2).
// Fused QKV (grid.y = 24): wsel = by>>3 picks B/out; epilogue scatters bf16
// to (B,H,T,D); Q scaled by 1/sqrt(64)*log2(e) so attention uses exp2 raw.
// (R12: reverted to the R7 separate-prep_kv pipeline — two fusion attempts
// R10/R11 both lost to it; T2 conflict-swizzle not applicable per the
// 2-phase regime gate.)
// ---------------------------------------------------------------------------
__global__ __launch_bounds__(256) void gemm_qkv(const ushort* __restrict__ A,
                                                const ushort* __restrict__ B0,
                                                const ushort* __restrict__ B1,
                                                const ushort* __restrict__ B2,
                                                ushort* __restrict__ Oq,
                                                ushort* __restrict__ Ok,
                                                ushort* __restrict__ Ov) {
    __shared__ __align__(16) ushort As[128 * 32];
    __shared__ __align__(16) ushort Bs[128 * 32];

    const int tid = threadIdx.x;
    const int wave = tid >> 6, lane = tid & 63;
    const int quad = lane >> 4, l16 = lane & 15;
    const int wm = wave >> 1, wn = wave & 1;

    const int bm = blockIdx.x * 128;
    const int by = blockIdx.y;
    const int wsel = by >> 3;
    const ushort* Bp = (wsel == 0) ? B0 : (wsel == 1) ? B1 : B2;
    const int bn = (by & 7) * 128;

    const int srow = lane >> 2;
    const int scol = (lane & 3) * 8;

    f32x4 acc[4][4];
#pragma unroll
    for (int i = 0; i < 4; i++)
#pragma unroll
        for (int j = 0; j < 4; j++) acc[i][j] = (f32x4){0.f, 0.f, 0.f, 0.f};

    for (int k0 = 0; k0 < CC; k0 += 32) {
#pragma unroll
        for (int i = 0; i < 2; i++) {
            const int rbase = wave * 32 + i * 16;
            gload_lds16(A + (size_t)(bm + rbase + srow) * CC + k0 + scol,
                        As + rbase * 32);
            gload_lds16(Bp + (size_t)(bn + rbase + srow) * CC + k0 + scol,
                        Bs + rbase * 32);
        }
        __syncthreads();

        bf16x8 af[4], bf[4];
#pragma unroll
        for (int mi = 0; mi < 4; mi++)
            af[mi] = *(const bf16x8*)(As + (wm * 64 + mi * 16 + l16) * 32 + quad * 8);
#pragma unroll
        for (int ni = 0; ni < 4; ni++)
            bf[ni] = *(const bf16x8*)(Bs + (wn * 64 + ni * 16 + l16) * 32 + quad * 8);
#pragma unroll
        for (int mi = 0; mi < 4; mi++)
#pragma unroll
            for (int ni = 0; ni < 4; ni++)
                acc[mi][ni] = __builtin_amdgcn_mfma_f32_16x16x32_bf16(
                    af[mi], bf[ni], acc[mi][ni], 0, 0, 0);
        __syncthreads();
    }

#pragma unroll
    for (int mi = 0; mi < 4; mi++) {
#pragma unroll
        for (int r = 0; r < 4; r++) {
            const int m = bm + wm * 64 + mi * 16 + quad * 4 + r;
#pragma unroll
            for (int ni = 0; ni < 4; ni++) {
                const int colg = bn + wn * 64 + ni * 16 + l16;
                float v = acc[mi][ni][r];
                if (wsel == 0) v *= 0.18033688f;  // 1/sqrt(64) * log2(e)
                const int t = m >> 1, b = m & 1;
                const int h = colg >> 6, d = colg & 63;
                ushort* dst = (wsel == 0) ? Oq : (wsel == 1) ? Ok : Ov;
                dst[(((size_t)(b * HH + h)) * TT + t) * DD + d] = f2b(v);
            }
        }
    }
}

// ---------------------------------------------------------------------------
// Out-projection GEMM: 128x64 tile (512 blocks = 2/CU), BK=32, fp32 output.
// ---------------------------------------------------------------------------
__global__ __launch_bounds__(256) void gemm_out(const ushort* __restrict__ A,
                                                const ushort* __restrict__ Bm,
                                                float* __restrict__ Of) {
    __shared__ __align__(16) ushort As[128 * 32];   // 8 KB
    __shared__ __align__(16) ushort Bs[64 * 32];    // 4 KB

    const int tid = threadIdx.x;
    const int wave = tid >> 6, lane = tid & 63;
    const int quad = lane >> 4, l16 = lane & 15;

    const int bm = blockIdx.x * 128;
    const int bn = blockIdx.y * 64;

    const int srow = lane >> 2;
    const int scol = (lane & 3) * 8;

    f32x4 acc[2][4];
#pragma unroll
    for (int i = 0; i < 2; i++)
#pragma unroll
        for (int j = 0; j < 4; j++) acc[i][j] = (f32x4){0.f, 0.f, 0.f, 0.f};

    for (int k0 = 0; k0 < CC; k0 += 32) {
#pragma unroll
        for (int i = 0; i < 2; i++) {
            const int rbase = wave * 32 + i * 16;
            gload_lds16(A + (size_t)(bm + rbase + srow) * CC + k0 + scol,
                        As + rbase * 32);
        }
        gload_lds16(Bm + (size_t)(bn + wave * 16 + srow) * CC + k0 + scol,
                    Bs + wave * 16 * 32);
        __syncthreads();

        bf16x8 af[2], bf[4];
#pragma unroll
        for (int mi = 0; mi < 2; mi++)
            af[mi] = *(const bf16x8*)(As + (wave * 32 + mi * 16 + l16) * 32 + quad * 8);
#pragma unroll
        for (int ni = 0; ni < 4; ni++)
            bf[ni] = *(const bf16x8*)(Bs + (ni * 16 + l16) * 32 + quad * 8);
#pragma unroll
        for (int mi = 0; mi < 2; mi++)
#pragma unroll
            for (int ni = 0; ni < 4; ni++)
                acc[mi][ni] = __builtin_amdgcn_mfma_f32_16x16x32_bf16(
                    af[mi], bf[ni], acc[mi][ni], 0, 0, 0);
        __syncthreads();
    }

#pragma unroll
    for (int mi = 0; mi < 2; mi++)
#pragma unroll
        for (int r = 0; r < 4; r++) {
            const int m = bm + wave * 32 + mi * 16 + quad * 4 + r;
#pragma unroll
            for (int ni = 0; ni < 4; ni++)
                Of[(size_t)m * CC + bn + ni * 16 + l16] = acc[mi][ni][r];
        }
}

// ---------------------------------------------------------------------------
// prep_kv: rewrite K and V into MFMA-fragment-major layout per 64-key tile:
//   Kf[bh][tile][c][nb][lane][u] = K[j=nb*16+(lane&15)][k=c*32+(lane>>4)*8+u]
//     (A-operand of the SWAPPED QK: row = key, k = d)
//   Vf[bh][tile][c][db][lane][u] = V[j=kappa][d=db*16+(lane&15)],
//     kappa(c,quad,u) = 16*((8c+u)>>2) + 4*quad + (u&3)
//     chosen so the PV A-operand packs from each lane's OWN 16 post-softmax
//     values (swapped-QK output) with zero cross-lane traffic.
// ---------------------------------------------------------------------------
__global__ __launch_bounds__(256) void prep_kv(const ushort* __restrict__ Kb,
                                               const ushort* __restrict__ Vb,
                                               ushort* __restrict__ Kf,
                                               ushort* __restrict__ Vf) {
    __shared__ __align__(16) ushort Ls[64 * 72];
    const int tile = blockIdx.x;      // 0..31
    const int bh   = blockIdx.y;
    const int t    = threadIdx.x;
    const size_t src = (size_t)bh * TT * DD + (size_t)tile * 64 * DD;
    const size_t dst = (size_t)bh * TT * DD + (size_t)tile * 4096;

    // ---- K: stage tile (coalesced), emit fragment-major (coalesced) ----
#pragma unroll
    for (int i = 0; i < 2; i++) {
        int e = t + i * 256;
        int r = e >> 3, kc = (e & 7) * 8;
        *(uint4*)(Ls + r * 72 + kc) = *(const uint4*)(Kb + src + r * 64 + kc);
    }
    __syncthreads();
#pragma unroll
    for (int i = 0; i < 2; i++) {
        int o = t + i * 256;          // output 16B chunk id, 0..511
        int c = o >> 8, nb = (o >> 6) & 3, lane = o & 63;
        int quad = lane >> 4, l16 = lane & 15;
        int j = nb * 16 + l16, k0 = c * 32 + quad * 8;
        *(uint4*)(Kf + dst + (size_t)o * 8) = *(const uint4*)(Ls + j * 72 + k0);
    }
    __syncthreads();

    // ---- V: stage tile, emit transposed+permuted fragment-major ----
#pragma unroll
    for (int i = 0; i < 2; i++) {
        int e = t + i * 256;
        int r = e >> 3, kc = (e & 7) * 8;
        *(uint4*)(Ls + r * 72 + kc) = *(const uint4*)(Vb + src + r * 64 + kc);
    }
    __syncthreads();
#pragma unroll
    for (int i = 0; i < 2; i++) {
        int o = t + i * 256;
        int c = o >> 8, db = (o >> 6) & 3, lane = o & 63;
        int quad = lane >> 4, l16 = lane & 15;
        int d = db * 16 + l16;
        ushort tmp[8];
#pragma unroll
        for (int u = 0; u < 8; u++) {
            int j = 16 * ((8 * c + u) >> 2) + 4 * quad + (u & 3);   // kappa
            tmp[u] = Ls[j * 72 + d];
        }
        *(uint4*)(Vf + dst + (size_t)o * 8) = *(uint4*)tmp;
    }
}

// ---------------------------------------------------------------------------
// Flash step with SWAPPED QK^T and fully in-register softmax.
//   S[nb] = mfma(kf[c*4+nb], qa[c], S[nb])  -> lane (quad,l16) holds
//   P[key=j0+16nb+4quad+r][query=q0+l16]: 16 P-values per lane, one query.
//   exp2 + l-sum in-lane; PV A-operand packed from the lane's own values
//   (V permutation kappa matches), 8 cvt_pk, zero cross-lane.
// R12: T5 s_setprio(1) wraps both MFMA clusters — waves on a CU drift
// within a step (long VALU softmax between clusters), so the scheduler
// can prefer the MFMA-issuing wave (m191: attn +4-7%).
// ---------------------------------------------------------------------------
template <bool DIAG>
__device__ __forceinline__ void attn_step(const bf16x8* qa, f32x4* O, float& l,
                                          const bf16x8* kf, const bf16x8* vf,
                                          int j0, int qg, int quad) {
    f32x4 S[4];
#pragma unroll
    for (int nb = 0; nb < 4; nb++) S[nb] = (f32x4){0.f, 0.f, 0.f, 0.f};
    __builtin_amdgcn_s_setprio(1);
#pragma unroll
    for (int c = 0; c < 2; c++)
#pragma unroll
        for (int nb = 0; nb < 4; nb++)
            S[nb] = __builtin_amdgcn_mfma_f32_16x16x32_bf16(kf[c * 4 + nb],
                                                            qa[c], S[nb], 0, 0, 0);
    __builtin_amdgcn_s_setprio(0);

    float p[4][4];   // [nb][r], key = j0 + nb*16 + quad*4 + r
#pragma unroll
    for (int nb = 0; nb < 4; nb++)
#pragma unroll
        for (int r = 0; r < 4; r++) {
            float s = S[nb][r];
            if (DIAG) { if (j0 + nb * 16 + quad * 4 + r > qg) s = -1e30f; }
            p[nb][r] = __builtin_amdgcn_exp2f(s);
        }
#pragma unroll
    for (int nb = 0; nb < 4; nb++)
        l += (p[nb][0] + p[nb][1]) + (p[nb][2] + p[nb][3]);

    // PV A-operand: dword w of pa[c] covers kslots u=2w,2w+1 ->
    // nb = 2c + (w>>1), r = (w&1)*2 + {0,1}  (matches kappa layout)
    union { unsigned w[4]; bf16x8 v; } pa0, pa1;
#pragma unroll
    for (int w = 0; w < 4; w++) {
        const int nb = w >> 1;
        const int rb = (w & 1) * 2;
        pa0.w[w] = pack_bf16(p[nb][rb], p[nb][rb + 1]);
        pa1.w[w] = pack_bf16(p[2 + nb][rb], p[2 + nb][rb + 1]);
    }
    __builtin_amdgcn_s_setprio(1);
#pragma unroll
    for (int db = 0; db < 4; db++)
        O[db] = __builtin_amdgcn_mfma_f32_16x16x32_bf16(pa0.v, vf[db], O[db], 0, 0, 0);
#pragma unroll
    for (int db = 0; db < 4; db++)
        O[db] = __builtin_amdgcn_mfma_f32_16x16x32_bf16(pa1.v, vf[4 + db], O[db], 0, 0, 0);
    __builtin_amdgcn_s_setprio(0);
}

// ---------------------------------------------------------------------------
// Paired-tile flash MFMA attention: in-register softmax + LDS-staged K/V
// double-buffer (the R7 known-best structure).
// LDS: 2 x 16KB = 32KB/block, 2 blocks/CU. XCD decode: xcd owns bh in
// [4*xcd, 4*xcd+4) (2MB K/V per L2).
// ---------------------------------------------------------------------------
__global__ __launch_bounds__(256, 2) void attn_mfma(const ushort* __restrict__ Qb,
                                                    const ushort* __restrict__ Kf,
                                                    const ushort* __restrict__ Vf,
                                                    ushort* __restrict__ ctx) {
    __shared__ __align__(16) ushort KV[2][8192];  // [buf][chunks 0-7 K, 8-15 V]

    const int tid  = threadIdx.x;
    const int wave = tid >> 6;
    const int lane = tid & 63;
    const int quad = lane >> 4;
    const int l16  = lane & 15;

    // XCD-locality decode: xcd = bidx&7 owns bh in [4*xcd, 4*xcd+4)
    const int bidx = blockIdx.x;                  // 0..511
    const int xcd  = bidx & 7;
    const int slot = bidx >> 3;                   // 0..63
    const int bh   = xcd * 4 + (slot >> 4);       // 0..31
    const int p    = slot & 15;                   // 0..15

    const int qtA = p, qtB = (TT / 64 - 1) - p;   // qtA < 16 <= qtB
    const int q0A = qtA * 64 + wave * 16;
    const int q0B = qtB * 64 + wave * 16;
    const int qgA = q0A + l16;                    // this lane's A query
    const int qgB = q0B + l16;                    // this lane's B query

    const size_t baseQK = (size_t)bh * TT * DD;

    bf16x8 qaA[2], qaB[2];
    {
        const ushort* qp = Qb + baseQK + (size_t)(q0A + l16) * DD + quad * 8;
        qaA[0] = *(const bf16x8*)(qp);
        qaA[1] = *(const bf16x8*)(qp + 32);
        const ushort* qp2 = Qb + baseQK + (size_t)(q0B + l16) * DD + quad * 8;
        qaB[0] = *(const bf16x8*)(qp2);
        qaB[1] = *(const bf16x8*)(qp2 + 32);
    }

    f32x4 OA[4], OB[4];
#pragma unroll
    for (int i = 0; i < 4; i++) {
        OA[i] = (f32x4){0.f, 0.f, 0.f, 0.f};
        OB[i] = (f32x4){0.f, 0.f, 0.f, 0.f};
    }
    float lA = 0.f, lB = 0.f;   // per-lane partial denom (query = q0+l16)

    const ushort* Kfp = Kf + baseQK;   // +4096 per tile
    const ushort* Vfp = Vf + baseQK;

    // stage one 16KB K/V tile into KV[buf]: wave w DMAs K chunks {2w,2w+1}
    // and V chunks {2w,2w+1} (wave-uniform LDS base + lane*16B, linear).
    auto stage = [&](int buf, const ushort* kp, const ushort* vp) {
#pragma unroll
        for (int i = 0; i < 2; i++) {
            const int ch = wave * 2 + i;           // 0..7 across 4 waves
            gload_lds16(kp + (ch << 9) + lane * 8, &KV[buf][ch << 9]);
            gload_lds16(vp + (ch << 9) + lane * 8, &KV[buf][(8 + ch) << 9]);
        }
    };

    stage(0, Kfp, Vfp);
    __syncthreads();

    int cur = 0;
    for (int kt = 0; kt <= qtB; kt++) {
        // issue next tile's DMA before touching this tile's data
        if (kt < qtB) stage(cur ^ 1, Kfp + 4096, Vfp + 4096);

        // fragment loads from LDS: contiguous 1KB per chunk, lane*16B apart
        bf16x8 kf[8], vf[8];
#pragma unroll
        for (int i = 0; i < 8; i++) {
            kf[i] = *(const bf16x8*)(&KV[cur][i << 9] + lane * 8);
            vf[i] = *(const bf16x8*)(&KV[cur][(8 + i) << 9] + lane * 8);
        }

        const int j0 = kt * 64;
        if (kt == qtB)
            attn_step<true >(qaB, OB, lB, kf, vf, j0, qgB, quad);
        else
            attn_step<false>(qaB, OB, lB, kf, vf, j0, qgB, quad);

        if (kt < qtA)
            attn_step<false>(qaA, OA, lA, kf, vf, j0, qgA, quad);
        else if (kt == qtA)
            attn_step<true >(qaA, OA, lA, kf, vf, j0, qgA, quad);

        __syncthreads();   // publishes buf cur^1; protects cur for overwrite
        cur ^= 1;
        Kfp += 4096;
        Vfp += 4096;
    }

    // epilogue: complete l across the 4 quads holding this query's keys,
    // then fetch the denom for the queries THIS lane's O rows belong to.
    lA += __shfl_xor(lA, 16); lA += __shfl_xor(lA, 32);
    lB += __shfl_xor(lB, 16); lB += __shfl_xor(lB, 32);

    const int b = bh >> 4, h = bh & 15;
#pragma unroll
    for (int r = 0; r < 4; r++) {
        const float invA = 1.f / __shfl(lA, quad * 4 + r);
        const float invB = 1.f / __shfl(lB, quad * 4 + r);
        const int tA = q0A + quad * 4 + r;
        const int tB = q0B + quad * 4 + r;
#pragma unroll
        for (int db = 0; db < 4; db++) {
            ctx[((size_t)tA * BB + b) * CC + h * DD + db * 16 + l16] =
                f2b(OA[db][r] * invA);
            ctx[((size_t)tB * BB + b) * CC + h * DD + db * 16 + l16] =
                f2b(OB[db][r] * invB);
        }
    }
}

// ---------------------------------------------------------------------------
extern "C" void kernel_launch(void* const* d_in, const int* in_sizes, int n_in,
                              void* d_out, int out_size, void* d_ws, size_t ws_size,
                              hipStream_t stream) {
    const float* x  = (const float*)d_in[0];
    const float* Wq = (const float*)d_in[1];
    const float* Wk = (const float*)d_in[2];
    const float* Wv = (const float*)d_in[3];
    const float* Wo = (const float*)d_in[4];
    float* out = (float*)d_out;

    // Workspace (bf16): xb 8MB | Wb 8MB | Qb 8 | Kb 8 | Vb 8 | Kf 8 | Vf 8 | Ctxb 8 = 64MB
    ushort* xb  = (ushort*)d_ws;
    ushort* Wb  = xb + (size_t)MM * CC;
    ushort* Wqb = Wb;
    ushort* Wkb = Wb + (size_t)CC * CC;
    ushort* Wvb = Wb + 2 * (size_t)CC * CC;
    ushort* Wob = Wb + 3 * (size_t)CC * CC;
    ushort* Qb  = Wb + 4 * (size_t)CC * CC;
    ushort* Kb  = Qb + (size_t)MM * CC;
    ushort* Vb  = Kb + (size_t)MM * CC;
    ushort* Kf  = Vb + (size_t)MM * CC;
    ushort* Vf  = Kf + (size_t)MM * CC;
    ushort* Ctxb = Vf + (size_t)MM * CC;

    conv_all<<<dim3((XQUADS + 4 * WQUADS) / 256), 256, 0, stream>>>(
        x, Wq, Wk, Wv, Wo, xb);

    gemm_qkv<<<dim3(MM / 128, 24), 256, 0, stream>>>(
        xb, Wqb, Wkb, Wvb, Qb, Kb, Vb);

    prep_kv<<<dim3(TT / 64, BB * HH), 256, 0, stream>>>(Kb, Vb, Kf, Vf);

    attn_mfma<<<dim3(512), 256, 0, stream>>>(Qb, Kf, Vf, Ctxb);

    gemm_out<<<dim3(MM / 128, CC / 64), 256, 0, stream>>>(Ctxb, Wob, out);
}